// Round 16
// baseline (191.469 us; speedup 1.0000x reference)
//
#include <hip/hip_runtime.h>
#include <hip/hip_bf16.h>
#include <cstdio>

#define S_ 1024
#define H_ 1024
#define NH_ 16
#define DH_ 64
#define G_ 100

typedef __attribute__((ext_vector_type(8))) short bf16x8;
typedef __attribute__((ext_vector_type(4))) short bf16x4;
typedef __attribute__((ext_vector_type(4))) float f32x4;

__device__ __forceinline__ f32x4 mfma16(bf16x8 a, bf16x8 b, f32x4 c) {
  return __builtin_amdgcn_mfma_f32_16x16x32_bf16(a, b, c, 0, 0, 0);
}

__device__ __forceinline__ short f2bf(float f) {
  union { float f; unsigned int i; } x;
  x.f = f;
  unsigned int r = x.i + 0x7fff + ((x.i >> 16) & 1);  // RNE
  return (short)(r >> 16);
}

// packed f32x2 -> bf16x2, gfx950 hardware instruction (T12 recipe)
__device__ __forceinline__ unsigned cvtpk(float lo, float hi) {
  unsigned r;
  asm("v_cvt_pk_bf16_f32 %0, %1, %2" : "=v"(r) : "v"(lo), "v"(hi));
  return r;
}

// hardware 2^x (v_exp_f32 computes exp2 natively)
__device__ __forceinline__ float exp2hw(float x) {
  float r;
  asm("v_exp_f32 %0, %1" : "=v"(r) : "v"(x));
  return r;
}

// async global->LDS, 16B per lane
__device__ __forceinline__ void gload16(const void* g, void* l) {
  __builtin_amdgcn_global_load_lds(
      (const __attribute__((address_space(1))) unsigned int*)g,
      (__attribute__((address_space(3))) unsigned int*)l, 16, 0, 0);
}

// ------- key compaction: idx[b][j] = orig pos of j-th UNMASKED key ---------
// cnts[b] = count; cnts[4+b] = count of unmasked keys with orig < G_.
__global__ __launch_bounds__(256) void compact(
    const int* __restrict__ mask, int* __restrict__ idx,
    int* __restrict__ cnts) {
  __shared__ int ps[256];
  __shared__ int scnt;
  const int b = blockIdx.x, t = threadIdx.x;
  int4 mv = reinterpret_cast<const int4*>(mask + b * S_)[t];
  const int k0 = (mv.x == 0), k1 = (mv.y == 0), k2 = (mv.z == 0),
            k3 = (mv.w == 0);
  const int c = k0 + k1 + k2 + k3;
  ps[t] = c;
  __syncthreads();
  for (int off = 1; off < 256; off <<= 1) {   // Hillis-Steele inclusive scan
    int v = (t >= off) ? ps[t - off] : 0;
    __syncthreads();
    ps[t] += v;
    __syncthreads();
  }
  int j = ps[t] - c;                           // exclusive prefix
  const int s0 = t * 4;
  if (k0) idx[b * S_ + j++] = s0;
  if (k1) idx[b * S_ + j++] = s0 + 1;
  if (k2) idx[b * S_ + j++] = s0 + 2;
  if (k3) idx[b * S_ + j++] = s0 + 3;
  if (t == 255) {
    scnt = ps[255];
    cnts[b] = ps[255];
  }
  __syncthreads();
  for (int j2 = scnt + t; j2 < S_; j2 += 256) idx[b * S_ + j2] = 0;
  int c100 = (k0 && s0 < G_) + (k1 && s0 + 1 < G_) + (k2 && s0 + 2 < G_) +
             (k3 && s0 + 3 < G_);
  ps[t] = c100;
  __syncthreads();
  for (int off = 128; off > 0; off >>= 1) {
    if (t < off) ps[t] += ps[t + off];
    __syncthreads();
  }
  if (t == 0) cnts[4 + b] = ps[0];
}

// ------- transpose + fp32->bf16 convert, 4 HxH weights: T[n][k] = W[k][n] ---
__global__ __launch_bounds__(256) void transpose_w(
    const float* __restrict__ W0, const float* __restrict__ W1,
    const float* __restrict__ W2, const float* __restrict__ W3,
    short* __restrict__ T0, short* __restrict__ T1,
    short* __restrict__ T2, short* __restrict__ T3) {
  __shared__ short tile[64][72];
  const float* W = (blockIdx.z == 0) ? W0 : (blockIdx.z == 1) ? W1
                 : (blockIdx.z == 2) ? W2 : W3;
  short* T = (blockIdx.z == 0) ? T0 : (blockIdx.z == 1) ? T1
           : (blockIdx.z == 2) ? T2 : T3;
  const int t = threadIdx.x;
  const int r0 = t >> 3;          // 0..31
  const int c8 = (t & 7) * 8;     // 0..56
  const int kbase = blockIdx.x * 64, nbase = blockIdx.y * 64;
#pragma unroll
  for (int p = 0; p < 2; ++p) {
    int r = p * 32 + r0;
    const float* src = W + (size_t)(kbase + r) * H_ + nbase + c8;
    f32x4 u0 = *reinterpret_cast<const f32x4*>(src);
    f32x4 u1 = *reinterpret_cast<const f32x4*>(src + 4);
#pragma unroll
    for (int j = 0; j < 4; ++j) {
      tile[r][c8 + j] = f2bf(u0[j]);
      tile[r][c8 + 4 + j] = f2bf(u1[j]);
    }
  }
  __syncthreads();
#pragma unroll
  for (int p = 0; p < 2; ++p) {
    int r = p * 32 + r0;          // n offset within tile
    bf16x8 o;
#pragma unroll
    for (int j = 0; j < 8; ++j) o[j] = tile[c8 + j][r];
    *reinterpret_cast<bf16x8*>(T + (size_t)(nbase + r) * H_ + kbase + c8) = o;
  }
}

// ---- QKV GEMM, NO-LDS: fragments loaded straight from global (L2-hot).
// 128x128 tile, 2x2 waves each 64x64, BK=32. A rows read as 2x16B fp32 +
// cvt_pk (per-row 64B-line coalesced); B rows read as 16B bf16. No barriers,
// no LDS: compiler freely software-pipelines loads across K-steps; latency
// hidden by 4 waves/SIMD occupancy. K/V rows gathered via idx (compaction);
// tiles past cnt skip to bias-only epilogue.
// z: 0 -> Qh (scale (1/8)*log2e, head layout), 1 -> Kh, 2 -> VhT.
__global__ __launch_bounds__(256) void qkvr(
    const float* __restrict__ A0, const float* __restrict__ A1,
    const float* __restrict__ A2, const short* __restrict__ W0,
    const short* __restrict__ W1, const short* __restrict__ W2,
    const float* __restrict__ b0, const float* __restrict__ b1,
    const float* __restrict__ b2, short* __restrict__ O0,
    short* __restrict__ O1, short* __restrict__ O2,
    const int* __restrict__ idx, const int* __restrict__ cnts) {
  const int z = blockIdx.z;
  const float* A  = (z == 0) ? A0 : (z == 1) ? A1 : A2;
  const short* Bt = (z == 0) ? W0 : (z == 1) ? W1 : W2;
  const float* bias = (z == 0) ? b0 : (z == 1) ? b1 : b2;
  short* Cb = (z == 0) ? O0 : (z == 1) ? O1 : O2;
  // Q pre-scale folds 1/sqrt(DH) AND log2(e) (attn uses exp2)
  const float scale = (z == 0) ? 0.18033688f : 1.0f;
  const int K = H_;
  const int t = threadIdx.x;
  const int l = t & 63, w = t >> 6;
  const int lr = l & 15, lg = l >> 4;
  const int wm = w >> 1, wn = w & 1;   // 2x2 waves, each 64x64
  const int bm = blockIdx.x * 128, bn = blockIdx.y * 128;
  const int bidx = bm >> 10;           // batch
  const int jrow = bm & 1023;          // tile's first compacted slot
  const int cnt = (z == 0) ? 1024 : cnts[bidx];
  f32x4 acc[4][4];
#pragma unroll
  for (int i = 0; i < 4; ++i)
#pragma unroll
    for (int j = 0; j < 4; ++j) acc[i][j] = (f32x4){0.f, 0.f, 0.f, 0.f};

  if (jrow < cnt) {                    // tile has live rows -> compute
    const int* idxb = idx + bidx * 1024;
    // per-lane A row pointers (gathered for K/V), col base lg*8
    const float* Ap[4];
    const short* Bp[4];
#pragma unroll
    for (int i = 0; i < 4; ++i) {
      const int j = jrow + wm * 64 + i * 16 + lr;
      const int srow = (z == 0) ? j : idxb[j];
      Ap[i] = A + ((size_t)(bidx << 10) + srow) * K + lg * 8;
      Bp[i] = Bt + (size_t)(bn + wn * 64 + i * 16 + lr) * K + lg * 8;
    }
#pragma unroll 2
    for (int kb = 0; kb < K; kb += 32) {
      bf16x8 af[4], bfr[4];
#pragma unroll
      for (int mi = 0; mi < 4; ++mi) {
        f32x4 alo = *reinterpret_cast<const f32x4*>(Ap[mi] + kb);
        f32x4 ahi = *reinterpret_cast<const f32x4*>(Ap[mi] + kb + 4);
        union { unsigned u[4]; bf16x8 v; } c;
        c.u[0] = cvtpk(alo[0], alo[1]);
        c.u[1] = cvtpk(alo[2], alo[3]);
        c.u[2] = cvtpk(ahi[0], ahi[1]);
        c.u[3] = cvtpk(ahi[2], ahi[3]);
        af[mi] = c.v;
      }
#pragma unroll
      for (int ni = 0; ni < 4; ++ni)
        bfr[ni] = *reinterpret_cast<const bf16x8*>(Bp[ni] + kb);
#pragma unroll
      for (int mi = 0; mi < 4; ++mi)
#pragma unroll
        for (int ni = 0; ni < 4; ++ni)
          acc[mi][ni] = mfma16(af[mi], bfr[ni], acc[mi][ni]);
    }
  }
#pragma unroll
  for (int mi = 0; mi < 4; ++mi)
#pragma unroll
    for (int ni = 0; ni < 4; ++ni) {
      int col = bn + wn * 64 + ni * 16 + lr;   // 0..1023 (global n)
      float bv = bias[col];
      int h = col >> 6, d = col & 63;
      if (z == 2) {                            // headT, packed s-contiguous
        int row0 = bm + wm * 64 + mi * 16 + lg * 4;
        int b = row0 >> 10, s0 = row0 & 1023;
        bf16x4 pk;
#pragma unroll
        for (int r = 0; r < 4; ++r) pk[r] = f2bf(acc[mi][ni][r] + bv);
        *reinterpret_cast<bf16x4*>(
            Cb + (((size_t)(b * NH_ + h)) * DH_ + d) * S_ + s0) = pk;
      } else {                                 // head layout [B,NH,S,DH]
#pragma unroll
        for (int r = 0; r < 4; ++r) {
          int row = bm + wm * 64 + mi * 16 + lg * 4 + r;
          int b = row >> 10, s = row & 1023;
          Cb[(((size_t)(b * NH_ + h)) * S_ + s) * DH_ + d] =
              f2bf((acc[mi][ni][r] + bv) * scale);
        }
      }
    }
}

// ---- out GEMM: 64x128 tile, BK=32, 2-phase double-buffered (24KB),
// conflict-free (row>>1)&3 swizzle, fp32 output ------------------------------
__global__ __launch_bounds__(256) void out64(
    const short* __restrict__ A, const short* __restrict__ Bt,
    const float* __restrict__ bias, float* __restrict__ Cf) {
  __shared__ short As[2][64 * 32];    // 2 x 4 KB
  __shared__ short Bs[2][128 * 32];   // 2 x 8 KB
  const int K = H_, N = H_;
  const int t = threadIdx.x;
  const int l = t & 63, w = t >> 6;
  const int lr = l & 15, lg = l >> 4;
  const int lk = (lr >> 1) & 3;
  const int wm = w >> 1, wn = w & 1;   // 2x2 waves, each 32x64
  const int bm = blockIdx.x * 64, bn = blockIdx.y * 128;
  f32x4 acc[2][4];
#pragma unroll
  for (int i = 0; i < 2; ++i)
#pragma unroll
    for (int j = 0; j < 4; ++j) acc[i][j] = (f32x4){0.f, 0.f, 0.f, 0.f};
  const int sr = t >> 2;              // 0..63 (stage row)
  const int ss = ((t & 3) ^ ((sr >> 1) & 3)) * 8;   // pre-swizzled src slot
  const short* Ab = A + (size_t)(bm + sr) * K + ss;
  const short* Bb = Bt + (size_t)(bn + sr) * K + ss;

  auto stage = [&](int buf, int kb) {
    gload16(Ab + kb, (char*)&As[buf][0] + t * 16);
    gload16(Bb + kb, (char*)&Bs[buf][0] + t * 16);
    gload16(Bb + (size_t)64 * K + kb, (char*)&Bs[buf][0] + 4096 + t * 16);
  };

  stage(0, 0);
  __syncthreads();
  const int NT = K >> 5;
  for (int tt = 0; tt < NT; ++tt) {
    const int cur = tt & 1;
    bf16x8 af[2], bfr[4];
#pragma unroll
    for (int mi = 0; mi < 2; ++mi) {
      const int row = wm * 32 + mi * 16 + lr;
      af[mi] = *reinterpret_cast<const bf16x8*>(
          &As[cur][row * 32 + ((lg ^ lk) * 8)]);
    }
#pragma unroll
    for (int ni = 0; ni < 4; ++ni) {
      const int rb = wn * 64 + ni * 16 + lr;
      bfr[ni] = *reinterpret_cast<const bf16x8*>(
          &Bs[cur][rb * 32 + ((lg ^ lk) * 8)]);
    }
    if (tt + 1 < NT) stage(cur ^ 1, (tt + 1) << 5);
#pragma unroll
    for (int mi = 0; mi < 2; ++mi)
#pragma unroll
      for (int ni = 0; ni < 4; ++ni)
        acc[mi][ni] = mfma16(af[mi], bfr[ni], acc[mi][ni]);
    __syncthreads();
  }
#pragma unroll
  for (int mi = 0; mi < 2; ++mi)
#pragma unroll
    for (int ni = 0; ni < 4; ++ni) {
      int col = bn + wn * 64 + ni * 16 + lr;
      float bv = bias[col];
#pragma unroll
      for (int r = 0; r < 4; ++r) {
        int row = bm + wm * 32 + mi * 16 + lg * 4 + r;
        Cf[(size_t)row * N + col] = acc[mi][ni][r] + bv;
      }
    }
}

// ---------------- flash attention over COMPACTED keys -----------------------
// Qh (pre-scaled by (1/8)*log2e), Kh/VhT hold compacted keys (slots 0..cnt-1
// live, rest finite garbage). p = exp2(s2 + mk), mk = (j<cnt) ? -16 : -1e9
// (shift cancels in p/sum; padded slots -> p = 0 exactly). Graph factor uses
// idx to recover the original key position (compaction is order-stable, so
// orig<100 keys are exactly compacted j < cnt100).
__global__ __launch_bounds__(256) void attn(
    const short* __restrict__ Qh, const short* __restrict__ Kh,
    const short* __restrict__ VhT, const float* __restrict__ graph,
    const int* __restrict__ idx, const int* __restrict__ cnts,
    short* __restrict__ ctx) {
  __shared__ short Kb[64 * 64];
  __shared__ short Vb[64 * 64];
  __shared__ short P[4 * 16 * 64];   // per-wave 16x64, XOR-swizzled, stride 64
  __shared__ float maskf[S_];
  // T1 chunked XCD swizzle: 8 XCDs x 128 contiguous gids
  const int lin = blockIdx.x;
  const int gid = (lin & 7) * 128 + (lin >> 3);
  const int bh = gid >> 4, qt = gid & 15;
  const int b = bh >> 4, h = bh & 15;
  const int t = threadIdx.x, w = t >> 6, l = t & 63;
  const int lr = l & 15, lg = l >> 4;
  const int lx = lr & 7;
  const int q0 = qt * 64 + w * 16;      // this wave's q base
  const int qg = q0 + lr;               // lane's q (score layout: col = q)
  short* Pw = P + w * 1024;
  const int cnt = cnts[b];
  const int cnt100 = cnts[4 + b];
  const int kend = ((cnt + 63) >> 6) << 6;
  const int* idxb = idx + b * 1024;
  const short* Qrow = Qh + ((size_t)bh * S_ + qg) * DH_;
  bf16x8 qf0 = *reinterpret_cast<const bf16x8*>(Qrow + lg * 8);
  bf16x8 qf1 = *reinterpret_cast<const bf16x8*>(Qrow + 32 + lg * 8);
  f32x4 o[4];
#pragma unroll
  for (int i = 0; i < 4; ++i) o[i] = (f32x4){0.f, 0.f, 0.f, 0.f};
  float llp = 0.f;

  // staging geometry: thread t handles row rs; logical granules ga, gb=ga^4
  const int rs = t >> 2;               // 0..63
  const int ga = (t & 3) + ((rs & 1) << 2);  // 0..7
  const int gb = ga ^ 4;
  const int sw0 = ((ga ^ (rs & 7)) * 8);
  const int sw1 = ((gb ^ (rs & 7)) * 8);
  const short* Ksrc0 = Kh + ((size_t)bh * S_ + rs) * DH_ + ga * 8;
  const short* Ksrc1 = Kh + ((size_t)bh * S_ + rs) * DH_ + gb * 8;
  const short* Vsrc0 = VhT + ((size_t)bh * DH_ + rs) * S_ + ga * 8;
  const short* Vsrc1 = VhT + ((size_t)bh * DH_ + rs) * S_ + gb * 8;

  // additive table (log2 domain) from compacted count:
  // j < cnt -> -16 (uniform shift), else -1e9 (exp2 -> exactly 0)
  {
    const int s0 = t * 4;
    f32x4 mo;
    mo.x = (s0 < cnt) ? -16.f : -1.0e9f;
    mo.y = (s0 + 1 < cnt) ? -16.f : -1.0e9f;
    mo.z = (s0 + 2 < cnt) ? -16.f : -1.0e9f;
    mo.w = (s0 + 3 < cnt) ? -16.f : -1.0e9f;
    reinterpret_cast<f32x4*>(maskf)[t] = mo;
  }
  // stage chunk 0
  {
    int4 ka = *reinterpret_cast<const int4*>(Ksrc0);
    int4 kb2 = *reinterpret_cast<const int4*>(Ksrc1);
    int4 va = *reinterpret_cast<const int4*>(Vsrc0);
    int4 vb2 = *reinterpret_cast<const int4*>(Vsrc1);
    *reinterpret_cast<int4*>(&Kb[rs * 64 + sw0]) = ka;
    *reinterpret_cast<int4*>(&Kb[rs * 64 + sw1]) = kb2;
    *reinterpret_cast<int4*>(&Vb[rs * 64 + sw0]) = va;
    *reinterpret_cast<int4*>(&Vb[rs * 64 + sw1]) = vb2;
  }
  __syncthreads();

  for (int kc = 0; kc < kend; kc += 64) {
    const bool pf = (kc + 64 < kend);
    int4 ka, kb2, va, vb2;
    if (pf) {                     // prefetch next chunk into registers (T14)
      ka = *reinterpret_cast<const int4*>(Ksrc0 + (size_t)(kc + 64) * DH_);
      kb2 = *reinterpret_cast<const int4*>(Ksrc1 + (size_t)(kc + 64) * DH_);
      va = *reinterpret_cast<const int4*>(Vsrc0 + kc + 64);
      vb2 = *reinterpret_cast<const int4*>(Vsrc1 + kc + 64);
    }
    // --- swapped QK^T from LDS: lane holds q=lr, k = mf*16+lg*4+r
    f32x4 sacc[4];
    __builtin_amdgcn_s_setprio(1);
#pragma unroll
    for (int mf = 0; mf < 4; ++mf) {
      const int rk = mf * 16 + lr;
      bf16x8 k0 = *reinterpret_cast<const bf16x8*>(
          &Kb[rk * 64 + ((lg ^ lx) * 8)]);
      bf16x8 k1 = *reinterpret_cast<const bf16x8*>(
          &Kb[rk * 64 + (((4 + lg) ^ lx) * 8)]);
      f32x4 sa = (f32x4){0.f, 0.f, 0.f, 0.f};
      sa = mfma16(k0, qf0, sa);
      sa = mfma16(k1, qf1, sa);
      sacc[mf] = sa;
    }
    __builtin_amdgcn_s_setprio(0);
    // --- graph factor (orig index via idx), additive mask, exp2, pack to P
    const bool gblk = (q0 < G_) && (kc < cnt100);
    const int pw0 = lr * 64 + (lg & 1) * 4;
#pragma unroll
    for (int mf = 0; mf < 4; ++mf) {
      f32x4 mk = *reinterpret_cast<const f32x4*>(&maskf[kc + mf * 16 + lg * 4]);
      f32x4 sa = sacc[mf];
      if (gblk) {
#pragma unroll
        for (int r = 0; r < 4; ++r) {
          int kgc = kc + mf * 16 + lg * 4 + r;
          if (qg < G_ && kgc < cnt100)
            sa[r] *= (1.f - graph[((size_t)b * G_ + qg) * G_ + idxb[kgc]]);
        }
      }
      float e0 = exp2hw(sa[0] + mk[0]);
      float e1 = exp2hw(sa[1] + mk[1]);
      float e2 = exp2hw(sa[2] + mk[2]);
      float e3 = exp2hw(sa[3] + mk[3]);
      llp += (e0 + e1) + (e2 + e3);
      int2 pk2;
      pk2.x = (int)cvtpk(e0, e1);
      pk2.y = (int)cvtpk(e2, e3);
      *reinterpret_cast<int2*>(
          &Pw[pw0 + (((2 * mf + (lg >> 1)) ^ lx) * 8)]) = pk2;
    }
    // --- PV from LDS: O[16q][64d] += P[16q,64k] @ V[64k,64d]
    __builtin_amdgcn_s_setprio(1);
#pragma unroll
    for (int ks = 0; ks < 2; ++ks) {
      bf16x8 pa = *reinterpret_cast<const bf16x8*>(
          &Pw[lr * 64 + (((ks * 4 + lg) ^ lx) * 8)]);
#pragma unroll
      for (int nf = 0; nf < 4; ++nf) {
        const int rv = nf * 16 + lr;
        bf16x8 vfr = *reinterpret_cast<const bf16x8*>(
            &Vb[rv * 64 + (((ks * 4 + lg) ^ lx) * 8)]);
        o[nf] = mfma16(pa, vfr, o[nf]);
      }
    }
    __builtin_amdgcn_s_setprio(0);
    if (pf) {
      __syncthreads();   // all waves done reading Kb/Vb for this chunk
      *reinterpret_cast<int4*>(&Kb[rs * 64 + sw0]) = ka;
      *reinterpret_cast<int4*>(&Kb[rs * 64 + sw1]) = kb2;
      *reinterpret_cast<int4*>(&Vb[rs * 64 + sw0]) = va;
      *reinterpret_cast<int4*>(&Vb[rs * 64 + sw1]) = vb2;
      __syncthreads();   // staged data visible
    }
  }
  // single cross-lane reduction at the end
  llp += __shfl_xor(llp, 16);
  llp += __shfl_xor(llp, 32);
  float rinv[4];
#pragma unroll
  for (int r = 0; r < 4; ++r)
    rinv[r] = __builtin_amdgcn_rcpf(__shfl(llp, lg * 4 + r, 64));
#pragma unroll
  for (int nf = 0; nf < 4; ++nf)
#pragma unroll
    for (int r = 0; r < 4; ++r) {
      float val = o[nf][r] * rinv[r];
      ctx[((size_t)b * S_ + q0 + lg * 4 + r) * H_ + h * DH_ + nf * 16 + lr] =
          f2bf(val);
    }
}

extern "C" void kernel_launch(void* const* d_in, const int* in_sizes, int n_in,
                              void* d_out, int out_size, void* d_ws, size_t ws_size,
                              hipStream_t stream) {
  const int B = in_sizes[0] / (S_ * H_);   // 4
  const int M = B * S_;                    // 4096
  const float* v    = (const float*)d_in[0];
  const float* k    = (const float*)d_in[1];
  const float* q    = (const float*)d_in[2];
  const int*   mask = (const int*)d_in[3];
  const float* graph= (const float*)d_in[4];
  const float* Wq   = (const float*)d_in[5];
  const float* bq   = (const float*)d_in[6];
  const float* Wk   = (const float*)d_in[7];
  const float* bk   = (const float*)d_in[8];
  const float* Wv   = (const float*)d_in[9];
  const float* bv   = (const float*)d_in[10];
  const float* Wm   = (const float*)d_in[11];
  const float* bm   = (const float*)d_in[12];

  short* ws = (short*)d_ws;
  const size_t WSZ = (size_t)H_ * H_;     // 1M elems per transposed weight
  const size_t TSZ = (size_t)M * H_;      // 4M elems per activation tensor
  short* WqT = ws;
  short* WkT = ws + WSZ;
  short* WvT = ws + 2 * WSZ;
  short* WmT = ws + 3 * WSZ;
  short* Qh  = ws + 4 * WSZ;
  short* Kh  = Qh + TSZ;
  short* VhT = Kh + TSZ;
  short* ctx = VhT + TSZ;
  int*   idxw = (int*)(ctx + TSZ);
  int*   cntw = idxw + 4 * 1024;
  if (ws_size < (4 * WSZ + 4 * TSZ) * sizeof(short) + (4 * 1024 + 8) * 4) {
    fprintf(stderr, "kernel_launch: ws too small (%zu)\n", ws_size);
    return;
  }

  compact<<<dim3(4), 256, 0, stream>>>(mask, idxw, cntw);
  transpose_w<<<dim3(H_ / 64, H_ / 64, 4), 256, 0, stream>>>(
      Wq, Wk, Wv, Wm, WqT, WkT, WvT, WmT);
  qkvr<<<dim3(M / 128, H_ / 128, 3), 256, 0, stream>>>(
      q, k, v, WqT, WkT, WvT, bq, bk, bv, Qh, Kh, VhT, idxw, cntw);
  attn<<<dim3(1024), 256, 0, stream>>>(Qh, Kh, VhT, graph, idxw, cntw, ctx);
  out64<<<dim3(M / 64, H_ / 128), 256, 0, stream>>>(
      ctx, WmT, bm, (float*)d_out);
}

// Round 17
// 110.107 us; speedup vs baseline: 1.7389x; 1.7389x over previous
//
#include <hip/hip_runtime.h>
#include <hip/hip_bf16.h>
#include <cstdio>

#define S_ 1024
#define H_ 1024
#define NH_ 16
#define DH_ 64
#define G_ 100

typedef __attribute__((ext_vector_type(8))) short bf16x8;
typedef __attribute__((ext_vector_type(4))) short bf16x4;
typedef __attribute__((ext_vector_type(4))) float f32x4;

__device__ __forceinline__ f32x4 mfma16(bf16x8 a, bf16x8 b, f32x4 c) {
  return __builtin_amdgcn_mfma_f32_16x16x32_bf16(a, b, c, 0, 0, 0);
}

__device__ __forceinline__ short f2bf(float f) {
  union { float f; unsigned int i; } x;
  x.f = f;
  unsigned int r = x.i + 0x7fff + ((x.i >> 16) & 1);  // RNE
  return (short)(r >> 16);
}

// packed f32x2 -> bf16x2, gfx950 hardware instruction (T12 recipe)
__device__ __forceinline__ unsigned cvtpk(float lo, float hi) {
  unsigned r;
  asm("v_cvt_pk_bf16_f32 %0, %1, %2" : "=v"(r) : "v"(lo), "v"(hi));
  return r;
}

// hardware 2^x (v_exp_f32 computes exp2 natively)
__device__ __forceinline__ float exp2hw(float x) {
  float r;
  asm("v_exp_f32 %0, %1" : "=v"(r) : "v"(x));
  return r;
}

// async global->LDS, 16B per lane
__device__ __forceinline__ void gload16(const void* g, void* l) {
  __builtin_amdgcn_global_load_lds(
      (const __attribute__((address_space(1))) unsigned int*)g,
      (__attribute__((address_space(3))) unsigned int*)l, 16, 0, 0);
}

// ------- key compaction: idx[b][j] = orig pos of j-th UNMASKED key ---------
// cnts[b] = count; cnts[4+b] = count of unmasked keys with orig < G_.
__global__ __launch_bounds__(256) void compact(
    const int* __restrict__ mask, int* __restrict__ idx,
    int* __restrict__ cnts) {
  __shared__ int ps[256];
  __shared__ int scnt;
  const int b = blockIdx.x, t = threadIdx.x;
  int4 mv = reinterpret_cast<const int4*>(mask + b * S_)[t];
  const int k0 = (mv.x == 0), k1 = (mv.y == 0), k2 = (mv.z == 0),
            k3 = (mv.w == 0);
  const int c = k0 + k1 + k2 + k3;
  ps[t] = c;
  __syncthreads();
  for (int off = 1; off < 256; off <<= 1) {   // Hillis-Steele inclusive scan
    int v = (t >= off) ? ps[t - off] : 0;
    __syncthreads();
    ps[t] += v;
    __syncthreads();
  }
  int j = ps[t] - c;                           // exclusive prefix
  const int s0 = t * 4;
  if (k0) idx[b * S_ + j++] = s0;
  if (k1) idx[b * S_ + j++] = s0 + 1;
  if (k2) idx[b * S_ + j++] = s0 + 2;
  if (k3) idx[b * S_ + j++] = s0 + 3;
  if (t == 255) {
    scnt = ps[255];
    cnts[b] = ps[255];
  }
  __syncthreads();
  for (int j2 = scnt + t; j2 < S_; j2 += 256) idx[b * S_ + j2] = 0;
  int c100 = (k0 && s0 < G_) + (k1 && s0 + 1 < G_) + (k2 && s0 + 2 < G_) +
             (k3 && s0 + 3 < G_);
  ps[t] = c100;
  __syncthreads();
  for (int off = 128; off > 0; off >>= 1) {
    if (t < off) ps[t] += ps[t + off];
    __syncthreads();
  }
  if (t == 0) cnts[4 + b] = ps[0];
}

// ------- transpose + fp32->bf16 convert, 4 HxH weights: T[n][k] = W[k][n] ---
__global__ __launch_bounds__(256) void transpose_w(
    const float* __restrict__ W0, const float* __restrict__ W1,
    const float* __restrict__ W2, const float* __restrict__ W3,
    short* __restrict__ T0, short* __restrict__ T1,
    short* __restrict__ T2, short* __restrict__ T3) {
  __shared__ short tile[64][72];
  const float* W = (blockIdx.z == 0) ? W0 : (blockIdx.z == 1) ? W1
                 : (blockIdx.z == 2) ? W2 : W3;
  short* T = (blockIdx.z == 0) ? T0 : (blockIdx.z == 1) ? T1
           : (blockIdx.z == 2) ? T2 : T3;
  const int t = threadIdx.x;
  const int r0 = t >> 3;          // 0..31
  const int c8 = (t & 7) * 8;     // 0..56
  const int kbase = blockIdx.x * 64, nbase = blockIdx.y * 64;
#pragma unroll
  for (int p = 0; p < 2; ++p) {
    int r = p * 32 + r0;
    const float* src = W + (size_t)(kbase + r) * H_ + nbase + c8;
    f32x4 u0 = *reinterpret_cast<const f32x4*>(src);
    f32x4 u1 = *reinterpret_cast<const f32x4*>(src + 4);
#pragma unroll
    for (int j = 0; j < 4; ++j) {
      tile[r][c8 + j] = f2bf(u0[j]);
      tile[r][c8 + 4 + j] = f2bf(u1[j]);
    }
  }
  __syncthreads();
#pragma unroll
  for (int p = 0; p < 2; ++p) {
    int r = p * 32 + r0;          // n offset within tile
    bf16x8 o;
#pragma unroll
    for (int j = 0; j < 8; ++j) o[j] = tile[c8 + j][r];
    *reinterpret_cast<bf16x8*>(T + (size_t)(nbase + r) * H_ + kbase + c8) = o;
  }
}

// ---- QKV GEMM, out64-clone structure: 64x128 tile, BK=32, 2-phase
// double-buffered (32KB: A fp32 2x8KB + B bf16 2x8KB), 4 gload16/thread/step,
// one __syncthreads per K-step. A fragments converted in-register via
// v_cvt_pk_bf16_f32; both tiles source-pre-swizzled (T2 / rule #21).
// K/V rows gathered via idx (compaction); tiles past cnt skip to bias-only
// epilogue (attn zeroes their contribution exactly).
// z: 0 -> Qh (scale (1/8)*log2e, head layout), 1 -> Kh, 2 -> VhT.
__global__ __launch_bounds__(256) void qkv64(
    const float* __restrict__ A0, const float* __restrict__ A1,
    const float* __restrict__ A2, const short* __restrict__ W0,
    const short* __restrict__ W1, const short* __restrict__ W2,
    const float* __restrict__ b0, const float* __restrict__ b1,
    const float* __restrict__ b2, short* __restrict__ O0,
    short* __restrict__ O1, short* __restrict__ O2,
    const int* __restrict__ idx, const int* __restrict__ cnts) {
  __shared__ float Af[2][64 * 32];    // 2 x 8 KB fp32 A tile
  __shared__ short Bs[2][128 * 32];   // 2 x 8 KB bf16 B tile
  const int z = blockIdx.z;
  const float* A  = (z == 0) ? A0 : (z == 1) ? A1 : A2;
  const short* Bt = (z == 0) ? W0 : (z == 1) ? W1 : W2;
  const float* bias = (z == 0) ? b0 : (z == 1) ? b1 : b2;
  short* Cb = (z == 0) ? O0 : (z == 1) ? O1 : O2;
  // Q pre-scale folds 1/sqrt(DH) AND log2(e) (attn uses exp2)
  const float scale = (z == 0) ? 0.18033688f : 1.0f;
  const int K = H_;
  const int t = threadIdx.x;
  const int l = t & 63, w = t >> 6;
  const int lr = l & 15, lg = l >> 4;
  const int lx = lr & 7;
  const int lk = (lr >> 1) & 3;
  const int wm = w >> 1, wn = w & 1;   // 2x2 waves, each 32x64
  const int bm = blockIdx.x * 64, bn = blockIdx.y * 128;
  const int bidx = bm >> 10;           // batch
  const int jrow = bm & 1023;          // tile's first compacted slot
  const int cnt = (z == 0) ? 1024 : cnts[bidx];
  f32x4 acc[2][4];
#pragma unroll
  for (int i = 0; i < 2; ++i)
#pragma unroll
    for (int j = 0; j < 4; ++j) acc[i][j] = (f32x4){0.f, 0.f, 0.f, 0.f};

  if (jrow < cnt) {                    // tile has live rows -> compute
    const int* idxb = idx + bidx * 1024;
    // A staging: 2 passes of 4KB; pass p row = p*32 + (t>>3), 16B slot t&7.
    // Slot (row,s) holds global fp32 group s^(row&7)  (row&7 == (t>>3)&7).
    const int ar = t >> 3;             // 0..31
    const int asl = (t & 7) ^ (ar & 7);
    const float* Ap[2];
#pragma unroll
    for (int p = 0; p < 2; ++p) {
      const int j = jrow + p * 32 + ar;
      const int srow = (z == 0) ? j : idxb[j];
      Ap[p] = A + ((size_t)(bidx << 10) + srow) * K + asl * 4;
    }
    // B staging: 2 passes of 4KB; pass p row = p*64 + (t>>2), slot t&3.
    // Slot (row,s) holds global bf16 group s^((row>>1)&3).
    const int br = t >> 2;             // 0..63
    const short* Bb =
        Bt + (size_t)(bn + br) * K + ((t & 3) ^ ((br >> 1) & 3)) * 8;

    auto stage = [&](int buf, int kb) {
      gload16(Ap[0] + kb, (char*)&Af[buf][0] + t * 16);
      gload16(Ap[1] + kb, (char*)&Af[buf][0] + 4096 + t * 16);
      gload16(Bb + kb, (char*)&Bs[buf][0] + t * 16);
      gload16(Bb + (size_t)64 * K + kb, (char*)&Bs[buf][0] + 4096 + t * 16);
    };

    stage(0, 0);
    __syncthreads();
    const int NT = K >> 5;             // 32 steps of BK=32
    for (int tt = 0; tt < NT; ++tt) {
      const int cur = tt & 1;
      bf16x8 af[2], bfr[4];
#pragma unroll
      for (int mi = 0; mi < 2; ++mi) {
        const int row = wm * 32 + mi * 16 + lr;
        const float* Ar = &Af[cur][row * 32];
        f32x4 alo =
            *reinterpret_cast<const f32x4*>(Ar + (((lg * 2) ^ lx) * 4));
        f32x4 ahi =
            *reinterpret_cast<const f32x4*>(Ar + (((lg * 2 + 1) ^ lx) * 4));
        union { unsigned u[4]; bf16x8 v; } c;
        c.u[0] = cvtpk(alo[0], alo[1]);
        c.u[1] = cvtpk(alo[2], alo[3]);
        c.u[2] = cvtpk(ahi[0], ahi[1]);
        c.u[3] = cvtpk(ahi[2], ahi[3]);
        af[mi] = c.v;
      }
#pragma unroll
      for (int ni = 0; ni < 4; ++ni) {
        const int rb = wn * 64 + ni * 16 + lr;
        bfr[ni] = *reinterpret_cast<const bf16x8*>(
            &Bs[cur][rb * 32 + ((lg ^ lk) * 8)]);
      }
      if (tt + 1 < NT) stage(cur ^ 1, (tt + 1) << 5);
#pragma unroll
      for (int mi = 0; mi < 2; ++mi)
#pragma unroll
        for (int ni = 0; ni < 4; ++ni)
          acc[mi][ni] = mfma16(af[mi], bfr[ni], acc[mi][ni]);
      __syncthreads();
    }
  }
#pragma unroll
  for (int mi = 0; mi < 2; ++mi)
#pragma unroll
    for (int ni = 0; ni < 4; ++ni) {
      int col = bn + wn * 64 + ni * 16 + lr;   // 0..1023 (global n)
      float bv = bias[col];
      int h = col >> 6, d = col & 63;
      if (z == 2) {                            // headT, packed s-contiguous
        int row0 = bm + wm * 32 + mi * 16 + lg * 4;
        int b = row0 >> 10, s0 = row0 & 1023;
        bf16x4 pk;
#pragma unroll
        for (int r = 0; r < 4; ++r) pk[r] = f2bf(acc[mi][ni][r] + bv);
        *reinterpret_cast<bf16x4*>(
            Cb + (((size_t)(b * NH_ + h)) * DH_ + d) * S_ + s0) = pk;
      } else {                                 // head layout [B,NH,S,DH]
#pragma unroll
        for (int r = 0; r < 4; ++r) {
          int row = bm + wm * 32 + mi * 16 + lg * 4 + r;
          int b = row >> 10, s = row & 1023;
          Cb[(((size_t)(b * NH_ + h)) * S_ + s) * DH_ + d] =
              f2bf((acc[mi][ni][r] + bv) * scale);
        }
      }
    }
}

// ---- out GEMM: 64x128 tile, BK=32, 2-phase double-buffered (24KB),
// conflict-free (row>>1)&3 swizzle, fp32 output ------------------------------
__global__ __launch_bounds__(256) void out64(
    const short* __restrict__ A, const short* __restrict__ Bt,
    const float* __restrict__ bias, float* __restrict__ Cf) {
  __shared__ short As[2][64 * 32];    // 2 x 4 KB
  __shared__ short Bs[2][128 * 32];   // 2 x 8 KB
  const int K = H_, N = H_;
  const int t = threadIdx.x;
  const int l = t & 63, w = t >> 6;
  const int lr = l & 15, lg = l >> 4;
  const int lk = (lr >> 1) & 3;
  const int wm = w >> 1, wn = w & 1;   // 2x2 waves, each 32x64
  const int bm = blockIdx.x * 64, bn = blockIdx.y * 128;
  f32x4 acc[2][4];
#pragma unroll
  for (int i = 0; i < 2; ++i)
#pragma unroll
    for (int j = 0; j < 4; ++j) acc[i][j] = (f32x4){0.f, 0.f, 0.f, 0.f};
  const int sr = t >> 2;              // 0..63 (stage row)
  const int ss = ((t & 3) ^ ((sr >> 1) & 3)) * 8;   // pre-swizzled src slot
  const short* Ab = A + (size_t)(bm + sr) * K + ss;
  const short* Bb = Bt + (size_t)(bn + sr) * K + ss;

  auto stage = [&](int buf, int kb) {
    gload16(Ab + kb, (char*)&As[buf][0] + t * 16);
    gload16(Bb + kb, (char*)&Bs[buf][0] + t * 16);
    gload16(Bb + (size_t)64 * K + kb, (char*)&Bs[buf][0] + 4096 + t * 16);
  };

  stage(0, 0);
  __syncthreads();
  const int NT = K >> 5;
  for (int tt = 0; tt < NT; ++tt) {
    const int cur = tt & 1;
    bf16x8 af[2], bfr[4];
#pragma unroll
    for (int mi = 0; mi < 2; ++mi) {
      const int row = wm * 32 + mi * 16 + lr;
      af[mi] = *reinterpret_cast<const bf16x8*>(
          &As[cur][row * 32 + ((lg ^ lk) * 8)]);
    }
#pragma unroll
    for (int ni = 0; ni < 4; ++ni) {
      const int rb = wn * 64 + ni * 16 + lr;
      bfr[ni] = *reinterpret_cast<const bf16x8*>(
          &Bs[cur][rb * 32 + ((lg ^ lk) * 8)]);
    }
    if (tt + 1 < NT) stage(cur ^ 1, (tt + 1) << 5);
#pragma unroll
    for (int mi = 0; mi < 2; ++mi)
#pragma unroll
      for (int ni = 0; ni < 4; ++ni)
        acc[mi][ni] = mfma16(af[mi], bfr[ni], acc[mi][ni]);
    __syncthreads();
  }
#pragma unroll
  for (int mi = 0; mi < 2; ++mi)
#pragma unroll
    for (int ni = 0; ni < 4; ++ni) {
      int col = bn + wn * 64 + ni * 16 + lr;
      float bv = bias[col];
#pragma unroll
      for (int r = 0; r < 4; ++r) {
        int row = bm + wm * 32 + mi * 16 + lg * 4 + r;
        Cf[(size_t)row * N + col] = acc[mi][ni][r] + bv;
      }
    }
}

// ---------------- flash attention over COMPACTED keys -----------------------
// Qh (pre-scaled by (1/8)*log2e), Kh/VhT hold compacted keys (slots 0..cnt-1
// live, rest finite garbage). p = exp2(s2 + mk), mk = (j<cnt) ? -16 : -1e9
// (shift cancels in p/sum; padded slots -> p = 0 exactly). Graph factor uses
// idx to recover the original key position (compaction is order-stable, so
// orig<100 keys are exactly compacted j < cnt100).
__global__ __launch_bounds__(256) void attn(
    const short* __restrict__ Qh, const short* __restrict__ Kh,
    const short* __restrict__ VhT, const float* __restrict__ graph,
    const int* __restrict__ idx, const int* __restrict__ cnts,
    short* __restrict__ ctx) {
  __shared__ short Kb[64 * 64];
  __shared__ short Vb[64 * 64];
  __shared__ short P[4 * 16 * 64];   // per-wave 16x64, XOR-swizzled, stride 64
  __shared__ float maskf[S_];
  // T1 chunked XCD swizzle: 8 XCDs x 128 contiguous gids
  const int lin = blockIdx.x;
  const int gid = (lin & 7) * 128 + (lin >> 3);
  const int bh = gid >> 4, qt = gid & 15;
  const int b = bh >> 4, h = bh & 15;
  const int t = threadIdx.x, w = t >> 6, l = t & 63;
  const int lr = l & 15, lg = l >> 4;
  const int lx = lr & 7;
  const int q0 = qt * 64 + w * 16;      // this wave's q base
  const int qg = q0 + lr;               // lane's q (score layout: col = q)
  short* Pw = P + w * 1024;
  const int cnt = cnts[b];
  const int cnt100 = cnts[4 + b];
  const int kend = ((cnt + 63) >> 6) << 6;
  const int* idxb = idx + b * 1024;
  const short* Qrow = Qh + ((size_t)bh * S_ + qg) * DH_;
  bf16x8 qf0 = *reinterpret_cast<const bf16x8*>(Qrow + lg * 8);
  bf16x8 qf1 = *reinterpret_cast<const bf16x8*>(Qrow + 32 + lg * 8);
  f32x4 o[4];
#pragma unroll
  for (int i = 0; i < 4; ++i) o[i] = (f32x4){0.f, 0.f, 0.f, 0.f};
  float llp = 0.f;

  // staging geometry: thread t handles row rs; logical granules ga, gb=ga^4
  const int rs = t >> 2;               // 0..63
  const int ga = (t & 3) + ((rs & 1) << 2);  // 0..7
  const int gb = ga ^ 4;
  const int sw0 = ((ga ^ (rs & 7)) * 8);
  const int sw1 = ((gb ^ (rs & 7)) * 8);
  const short* Ksrc0 = Kh + ((size_t)bh * S_ + rs) * DH_ + ga * 8;
  const short* Ksrc1 = Kh + ((size_t)bh * S_ + rs) * DH_ + gb * 8;
  const short* Vsrc0 = VhT + ((size_t)bh * DH_ + rs) * S_ + ga * 8;
  const short* Vsrc1 = VhT + ((size_t)bh * DH_ + rs) * S_ + gb * 8;

  // additive table (log2 domain) from compacted count:
  // j < cnt -> -16 (uniform shift), else -1e9 (exp2 -> exactly 0)
  {
    const int s0 = t * 4;
    f32x4 mo;
    mo.x = (s0 < cnt) ? -16.f : -1.0e9f;
    mo.y = (s0 + 1 < cnt) ? -16.f : -1.0e9f;
    mo.z = (s0 + 2 < cnt) ? -16.f : -1.0e9f;
    mo.w = (s0 + 3 < cnt) ? -16.f : -1.0e9f;
    reinterpret_cast<f32x4*>(maskf)[t] = mo;
  }
  // stage chunk 0
  {
    int4 ka = *reinterpret_cast<const int4*>(Ksrc0);
    int4 kb2 = *reinterpret_cast<const int4*>(Ksrc1);
    int4 va = *reinterpret_cast<const int4*>(Vsrc0);
    int4 vb2 = *reinterpret_cast<const int4*>(Vsrc1);
    *reinterpret_cast<int4*>(&Kb[rs * 64 + sw0]) = ka;
    *reinterpret_cast<int4*>(&Kb[rs * 64 + sw1]) = kb2;
    *reinterpret_cast<int4*>(&Vb[rs * 64 + sw0]) = va;
    *reinterpret_cast<int4*>(&Vb[rs * 64 + sw1]) = vb2;
  }
  __syncthreads();

  for (int kc = 0; kc < kend; kc += 64) {
    const bool pf = (kc + 64 < kend);
    int4 ka, kb2, va, vb2;
    if (pf) {                     // prefetch next chunk into registers (T14)
      ka = *reinterpret_cast<const int4*>(Ksrc0 + (size_t)(kc + 64) * DH_);
      kb2 = *reinterpret_cast<const int4*>(Ksrc1 + (size_t)(kc + 64) * DH_);
      va = *reinterpret_cast<const int4*>(Vsrc0 + kc + 64);
      vb2 = *reinterpret_cast<const int4*>(Vsrc1 + kc + 64);
    }
    // --- swapped QK^T from LDS: lane holds q=lr, k = mf*16+lg*4+r
    f32x4 sacc[4];
    __builtin_amdgcn_s_setprio(1);
#pragma unroll
    for (int mf = 0; mf < 4; ++mf) {
      const int rk = mf * 16 + lr;
      bf16x8 k0 = *reinterpret_cast<const bf16x8*>(
          &Kb[rk * 64 + ((lg ^ lx) * 8)]);
      bf16x8 k1 = *reinterpret_cast<const bf16x8*>(
          &Kb[rk * 64 + (((4 + lg) ^ lx) * 8)]);
      f32x4 sa = (f32x4){0.f, 0.f, 0.f, 0.f};
      sa = mfma16(k0, qf0, sa);
      sa = mfma16(k1, qf1, sa);
      sacc[mf] = sa;
    }
    __builtin_amdgcn_s_setprio(0);
    // --- graph factor (orig index via idx), additive mask, exp2, pack to P
    const bool gblk = (q0 < G_) && (kc < cnt100);
    const int pw0 = lr * 64 + (lg & 1) * 4;
#pragma unroll
    for (int mf = 0; mf < 4; ++mf) {
      f32x4 mk = *reinterpret_cast<const f32x4*>(&maskf[kc + mf * 16 + lg * 4]);
      f32x4 sa = sacc[mf];
      if (gblk) {
#pragma unroll
        for (int r = 0; r < 4; ++r) {
          int kgc = kc + mf * 16 + lg * 4 + r;
          if (qg < G_ && kgc < cnt100)
            sa[r] *= (1.f - graph[((size_t)b * G_ + qg) * G_ + idxb[kgc]]);
        }
      }
      float e0 = exp2hw(sa[0] + mk[0]);
      float e1 = exp2hw(sa[1] + mk[1]);
      float e2 = exp2hw(sa[2] + mk[2]);
      float e3 = exp2hw(sa[3] + mk[3]);
      llp += (e0 + e1) + (e2 + e3);
      int2 pk2;
      pk2.x = (int)cvtpk(e0, e1);
      pk2.y = (int)cvtpk(e2, e3);
      *reinterpret_cast<int2*>(
          &Pw[pw0 + (((2 * mf + (lg >> 1)) ^ lx) * 8)]) = pk2;
    }
    // --- PV from LDS: O[16q][64d] += P[16q,64k] @ V[64k,64d]
    __builtin_amdgcn_s_setprio(1);
#pragma unroll
    for (int ks = 0; ks < 2; ++ks) {
      bf16x8 pa = *reinterpret_cast<const bf16x8*>(
          &Pw[lr * 64 + (((ks * 4 + lg) ^ lx) * 8)]);
#pragma unroll
      for (int nf = 0; nf < 4; ++nf) {
        const int rv = nf * 16 + lr;
        bf16x8 vfr = *reinterpret_cast<const bf16x8*>(
            &Vb[rv * 64 + (((ks * 4 + lg) ^ lx) * 8)]);
        o[nf] = mfma16(pa, vfr, o[nf]);
      }
    }
    __builtin_amdgcn_s_setprio(0);
    if (pf) {
      __syncthreads();   // all waves done reading Kb/Vb for this chunk
      *reinterpret_cast<int4*>(&Kb[rs * 64 + sw0]) = ka;
      *reinterpret_cast<int4*>(&Kb[rs * 64 + sw1]) = kb2;
      *reinterpret_cast<int4*>(&Vb[rs * 64 + sw0]) = va;
      *reinterpret_cast<int4*>(&Vb[rs * 64 + sw1]) = vb2;
      __syncthreads();   // staged data visible
    }
  }
  // single cross-lane reduction at the end
  llp += __shfl_xor(llp, 16);
  llp += __shfl_xor(llp, 32);
  float rinv[4];
#pragma unroll
  for (int r = 0; r < 4; ++r)
    rinv[r] = __builtin_amdgcn_rcpf(__shfl(llp, lg * 4 + r, 64));
#pragma unroll
  for (int nf = 0; nf < 4; ++nf)
#pragma unroll
    for (int r = 0; r < 4; ++r) {
      float val = o[nf][r] * rinv[r];
      ctx[((size_t)b * S_ + q0 + lg * 4 + r) * H_ + h * DH_ + nf * 16 + lr] =
          f2bf(val);
    }
}

extern "C" void kernel_launch(void* const* d_in, const int* in_sizes, int n_in,
                              void* d_out, int out_size, void* d_ws, size_t ws_size,
                              hipStream_t stream) {
  const int B = in_sizes[0] / (S_ * H_);   // 4
  const int M = B * S_;                    // 4096
  const float* v    = (const float*)d_in[0];
  const float* k    = (const float*)d_in[1];
  const float* q    = (const float*)d_in[2];
  const int*   mask = (const int*)d_in[3];
  const float* graph= (const float*)d_in[4];
  const float* Wq   = (const float*)d_in[5];
  const float* bq   = (const float*)d_in[6];
  const float* Wk   = (const float*)d_in[7];
  const float* bk   = (const float*)d_in[8];
  const float* Wv   = (const float*)d_in[9];
  const float* bv   = (const float*)d_in[10];
  const float* Wm   = (const float*)d_in[11];
  const float* bm   = (const float*)d_in[12];

  short* ws = (short*)d_ws;
  const size_t WSZ = (size_t)H_ * H_;     // 1M elems per transposed weight
  const size_t TSZ = (size_t)M * H_;      // 4M elems per activation tensor
  short* WqT = ws;
  short* WkT = ws + WSZ;
  short* WvT = ws + 2 * WSZ;
  short* WmT = ws + 3 * WSZ;
  short* Qh  = ws + 4 * WSZ;
  short* Kh  = Qh + TSZ;
  short* VhT = Kh + TSZ;
  short* ctx = VhT + TSZ;
  int*   idxw = (int*)(ctx + TSZ);
  int*   cntw = idxw + 4 * 1024;
  if (ws_size < (4 * WSZ + 4 * TSZ) * sizeof(short) + (4 * 1024 + 8) * 4) {
    fprintf(stderr, "kernel_launch: ws too small (%zu)\n", ws_size);
    return;
  }

  compact<<<dim3(4), 256, 0, stream>>>(mask, idxw, cntw);
  transpose_w<<<dim3(H_ / 64, H_ / 64, 4), 256, 0, stream>>>(
      Wq, Wk, Wv, Wm, WqT, WkT, WvT, WmT);
  qkv64<<<dim3(M / 64, H_ / 128, 3), 256, 0, stream>>>(
      q, k, v, WqT, WkT, WvT, bq, bk, bv, Qh, Kh, VhT, idxw, cntw);
  attn<<<dim3(1024), 256, 0, stream>>>(Qh, Kh, VhT, graph, idxw, cntw, ctx);
  out64<<<dim3(M / 64, H_ / 128), 256, 0, stream>>>(
      ctx, WmT, bm, (float*)d_out);
}

// Round 19
// 100.934 us; speedup vs baseline: 1.8970x; 1.0909x over previous
//
#include <hip/hip_runtime.h>
#include <hip/hip_bf16.h>
#include <cstdio>

#define S_ 1024
#define H_ 1024
#define NH_ 16
#define DH_ 64
#define G_ 100

typedef __attribute__((ext_vector_type(8))) short bf16x8;
typedef __attribute__((ext_vector_type(4))) short bf16x4;
typedef __attribute__((ext_vector_type(4))) float f32x4;

__device__ __forceinline__ f32x4 mfma16(bf16x8 a, bf16x8 b, f32x4 c) {
  return __builtin_amdgcn_mfma_f32_16x16x32_bf16(a, b, c, 0, 0, 0);
}

__device__ __forceinline__ short f2bf(float f) {
  union { float f; unsigned int i; } x;
  x.f = f;
  unsigned int r = x.i + 0x7fff + ((x.i >> 16) & 1);  // RNE
  return (short)(r >> 16);
}

// packed f32x2 -> bf16x2, gfx950 hardware instruction (T12 recipe)
__device__ __forceinline__ unsigned cvtpk(float lo, float hi) {
  unsigned r;
  asm("v_cvt_pk_bf16_f32 %0, %1, %2" : "=v"(r) : "v"(lo), "v"(hi));
  return r;
}

// hardware 2^x (v_exp_f32 computes exp2 natively)
__device__ __forceinline__ float exp2hw(float x) {
  float r;
  asm("v_exp_f32 %0, %1" : "=v"(r) : "v"(x));
  return r;
}

// async global->LDS, 16B per lane
__device__ __forceinline__ void gload16(const void* g, void* l) {
  __builtin_amdgcn_global_load_lds(
      (const __attribute__((address_space(1))) unsigned int*)g,
      (__attribute__((address_space(3))) unsigned int*)l, 16, 0, 0);
}

// ------- key compaction: idx[b][j] = orig pos of j-th UNMASKED key ---------
// cnts[b] = count; cnts[4+b] = count of unmasked keys with orig < G_.
__global__ __launch_bounds__(256) void compact(
    const int* __restrict__ mask, int* __restrict__ idx,
    int* __restrict__ cnts) {
  __shared__ int ps[256];
  __shared__ int scnt;
  const int b = blockIdx.x, t = threadIdx.x;
  int4 mv = reinterpret_cast<const int4*>(mask + b * S_)[t];
  const int k0 = (mv.x == 0), k1 = (mv.y == 0), k2 = (mv.z == 0),
            k3 = (mv.w == 0);
  const int c = k0 + k1 + k2 + k3;
  ps[t] = c;
  __syncthreads();
  for (int off = 1; off < 256; off <<= 1) {   // Hillis-Steele inclusive scan
    int v = (t >= off) ? ps[t - off] : 0;
    __syncthreads();
    ps[t] += v;
    __syncthreads();
  }
  int j = ps[t] - c;                           // exclusive prefix
  const int s0 = t * 4;
  if (k0) idx[b * S_ + j++] = s0;
  if (k1) idx[b * S_ + j++] = s0 + 1;
  if (k2) idx[b * S_ + j++] = s0 + 2;
  if (k3) idx[b * S_ + j++] = s0 + 3;
  if (t == 255) {
    scnt = ps[255];
    cnts[b] = ps[255];
  }
  __syncthreads();
  for (int j2 = scnt + t; j2 < S_; j2 += 256) idx[b * S_ + j2] = 0;
  int c100 = (k0 && s0 < G_) + (k1 && s0 + 1 < G_) + (k2 && s0 + 2 < G_) +
             (k3 && s0 + 3 < G_);
  ps[t] = c100;
  __syncthreads();
  for (int off = 128; off > 0; off >>= 1) {
    if (t < off) ps[t] += ps[t + off];
    __syncthreads();
  }
  if (t == 0) cnts[4 + b] = ps[0];
}

// ------- transpose + fp32->bf16 convert, 4 HxH weights: T[n][k] = W[k][n] ---
__global__ __launch_bounds__(256) void transpose_w(
    const float* __restrict__ W0, const float* __restrict__ W1,
    const float* __restrict__ W2, const float* __restrict__ W3,
    short* __restrict__ T0, short* __restrict__ T1,
    short* __restrict__ T2, short* __restrict__ T3) {
  __shared__ short tile[64][72];
  const float* W = (blockIdx.z == 0) ? W0 : (blockIdx.z == 1) ? W1
                 : (blockIdx.z == 2) ? W2 : W3;
  short* T = (blockIdx.z == 0) ? T0 : (blockIdx.z == 1) ? T1
           : (blockIdx.z == 2) ? T2 : T3;
  const int t = threadIdx.x;
  const int r0 = t >> 3;          // 0..31
  const int c8 = (t & 7) * 8;     // 0..56
  const int kbase = blockIdx.x * 64, nbase = blockIdx.y * 64;
#pragma unroll
  for (int p = 0; p < 2; ++p) {
    int r = p * 32 + r0;
    const float* src = W + (size_t)(kbase + r) * H_ + nbase + c8;
    f32x4 u0 = *reinterpret_cast<const f32x4*>(src);
    f32x4 u1 = *reinterpret_cast<const f32x4*>(src + 4);
#pragma unroll
    for (int j = 0; j < 4; ++j) {
      tile[r][c8 + j] = f2bf(u0[j]);
      tile[r][c8 + 4 + j] = f2bf(u1[j]);
    }
  }
  __syncthreads();
#pragma unroll
  for (int p = 0; p < 2; ++p) {
    int r = p * 32 + r0;          // n offset within tile
    bf16x8 o;
#pragma unroll
    for (int j = 0; j < 8; ++j) o[j] = tile[c8 + j][r];
    *reinterpret_cast<bf16x8*>(T + (size_t)(nbase + r) * H_ + kbase + c8) = o;
  }
}

// ---- QKV GEMM: 128x128 tile, BK=32, double-buffered 32KB (A bf16 reg-staged
// + B bf16 via global_load_lds), one __syncthreads per K-step.
// A path (T14 issue-early/write-late, 16 VGPRs in flight): global fp32 loads
// issued before MFMA, cvt_pk + ds_write after MFMA, landing in the barrier.
// Swizzle invariant (rule #21, BOTH sides): LDS[row][s] = global[row][s^key],
// key(row) = (row>>1)&3.  A: ds_write dest slot (t&3), SOURCE slot (t&3)^key.
// B: gload_lds dest linear (t*16) = slot (t&3), source slot (t&3)^key.
// Fragment reads use slot (lg ^ (lr>>1)&3) -> global group lg. K/V rows
// gathered via idx (compaction); tiles past cnt -> bias-only epilogue.
// z: 0 -> Qh (scale (1/8)*log2e, head layout), 1 -> Kh, 2 -> VhT.
__global__ __launch_bounds__(256, 4) void qkv128r(
    const float* __restrict__ A0, const float* __restrict__ A1,
    const float* __restrict__ A2, const short* __restrict__ W0,
    const short* __restrict__ W1, const short* __restrict__ W2,
    const float* __restrict__ b0, const float* __restrict__ b1,
    const float* __restrict__ b2, short* __restrict__ O0,
    short* __restrict__ O1, short* __restrict__ O2,
    const int* __restrict__ idx, const int* __restrict__ cnts) {
  __shared__ short Asb[2][128 * 32];  // 2 x 8 KB bf16 A tile
  __shared__ short Bs[2][128 * 32];   // 2 x 8 KB bf16 B tile
  const int z = blockIdx.z;
  const float* A  = (z == 0) ? A0 : (z == 1) ? A1 : A2;
  const short* Bt = (z == 0) ? W0 : (z == 1) ? W1 : W2;
  const float* bias = (z == 0) ? b0 : (z == 1) ? b1 : b2;
  short* Cb = (z == 0) ? O0 : (z == 1) ? O1 : O2;
  // Q pre-scale folds 1/sqrt(DH) AND log2(e) (attn uses exp2)
  const float scale = (z == 0) ? 0.18033688f : 1.0f;
  const int K = H_;
  const int t = threadIdx.x;
  const int l = t & 63, w = t >> 6;
  const int lr = l & 15, lg = l >> 4;
  const int lk = (lr >> 1) & 3;        // fragment swizzle key
  const int wm = w >> 1, wn = w & 1;   // 2x2 waves, each 64x64
  const int bm = blockIdx.x * 128, bn = blockIdx.y * 128;
  const int bidx = bm >> 10;           // batch
  const int jrow = bm & 1023;          // tile's first compacted slot
  const int cnt = (z == 0) ? 1024 : cnts[bidx];
  f32x4 acc[4][4];
#pragma unroll
  for (int i = 0; i < 4; ++i)
#pragma unroll
    for (int j = 0; j < 4; ++j) acc[i][j] = (f32x4){0.f, 0.f, 0.f, 0.f};

  if (jrow < cnt) {                    // tile has live rows -> compute
    const int* idxb = idx + bidx * 1024;
    // Staging geometry (A and B share it): pass p row = p*64 + (t>>2).
    // key = ((t>>2)>>1)&3, pass-invariant since 64 === 0 (mod 8).
    const int r0 = t >> 2;             // 0..63
    const int key = (r0 >> 1) & 3;
    const int ssrc = (t & 3) ^ key;    // pre-swizzled SOURCE slot
    const int j0 = jrow + r0;
    const int j1 = jrow + 64 + r0;
    const int sr0 = (z == 0) ? j0 : idxb[j0];
    const int sr1 = (z == 0) ? j1 : idxb[j1];
    const float* ApA = A + ((size_t)(bidx << 10) + sr0) * K + ssrc * 8;
    const float* ApB = A + ((size_t)(bidx << 10) + sr1) * K + ssrc * 8;
    const short* Bb = Bt + (size_t)(bn + r0) * K + ssrc * 8;
    // A dest: NATURAL slot (t&3)  ->  LDS[row][t&3] = global[row][(t&3)^key]
    short* dstA0[2] = {&Asb[0][r0 * 32 + (t & 3) * 8],
                       &Asb[1][r0 * 32 + (t & 3) * 8]};
    short* dstA1[2] = {&Asb[0][(64 + r0) * 32 + (t & 3) * 8],
                       &Asb[1][(64 + r0) * 32 + (t & 3) * 8]};

    f32x4 pa0, pa1, pa2, pa3;
    auto loadA = [&](int kb) {
      pa0 = *reinterpret_cast<const f32x4*>(ApA + kb);
      pa1 = *reinterpret_cast<const f32x4*>(ApA + kb + 4);
      pa2 = *reinterpret_cast<const f32x4*>(ApB + kb);
      pa3 = *reinterpret_cast<const f32x4*>(ApB + kb + 4);
    };
    auto writeA = [&](int buf) {
      union { unsigned u[4]; bf16x8 v; } c0, c1;
      c0.u[0] = cvtpk(pa0[0], pa0[1]);
      c0.u[1] = cvtpk(pa0[2], pa0[3]);
      c0.u[2] = cvtpk(pa1[0], pa1[1]);
      c0.u[3] = cvtpk(pa1[2], pa1[3]);
      c1.u[0] = cvtpk(pa2[0], pa2[1]);
      c1.u[1] = cvtpk(pa2[2], pa2[3]);
      c1.u[2] = cvtpk(pa3[0], pa3[1]);
      c1.u[3] = cvtpk(pa3[2], pa3[3]);
      *reinterpret_cast<bf16x8*>(dstA0[buf]) = c0.v;
      *reinterpret_cast<bf16x8*>(dstA1[buf]) = c1.v;
    };
    auto stageB = [&](int buf, int kb) {
      gload16(Bb + kb, (char*)&Bs[buf][0] + t * 16);
      gload16(Bb + (size_t)64 * K + kb, (char*)&Bs[buf][0] + 4096 + t * 16);
    };

    // prologue: fill buffer 0
    loadA(0);
    stageB(0, 0);
    writeA(0);
    __syncthreads();
    const int NT = K >> 5;             // 32 steps of BK=32
    for (int tt = 0; tt < NT; ++tt) {
      const int cur = tt & 1;
      // 1) fragment reads from cur
      bf16x8 af[4], bfr[4];
#pragma unroll
      for (int mi = 0; mi < 4; ++mi) {
        const int row = wm * 64 + mi * 16 + lr;
        af[mi] = *reinterpret_cast<const bf16x8*>(
            &Asb[cur][row * 32 + ((lg ^ lk) * 8)]);
      }
#pragma unroll
      for (int ni = 0; ni < 4; ++ni) {
        const int rb = wn * 64 + ni * 16 + lr;
        bfr[ni] = *reinterpret_cast<const bf16x8*>(
            &Bs[cur][rb * 32 + ((lg ^ lk) * 8)]);
      }
      // 2) issue next tile's loads (A->regs, B->LDS-DMA): fly through MFMA
      const bool nx = (tt + 1 < NT);
      if (nx) {
        const int kb = (tt + 1) << 5;
        loadA(kb);
        stageB(cur ^ 1, kb);
      }
      // 3) MFMA (register-only)
#pragma unroll
      for (int mi = 0; mi < 4; ++mi)
#pragma unroll
        for (int ni = 0; ni < 4; ++ni)
          acc[mi][ni] = mfma16(af[mi], bfr[ni], acc[mi][ni]);
      // 4) write-late: convert + ds_write next A tile (load latency covered
      //    by the MFMA block above), then one barrier drains everything
      if (nx) writeA(cur ^ 1);
      __syncthreads();
    }
  }
#pragma unroll
  for (int mi = 0; mi < 4; ++mi)
#pragma unroll
    for (int ni = 0; ni < 4; ++ni) {
      int col = bn + wn * 64 + ni * 16 + lr;   // 0..1023 (global n)
      float bv = bias[col];
      int h = col >> 6, d = col & 63;
      if (z == 2) {                            // headT, packed s-contiguous
        int row0 = bm + wm * 64 + mi * 16 + lg * 4;
        int b = row0 >> 10, s0 = row0 & 1023;
        bf16x4 pk;
#pragma unroll
        for (int r = 0; r < 4; ++r) pk[r] = f2bf(acc[mi][ni][r] + bv);
        *reinterpret_cast<bf16x4*>(
            Cb + (((size_t)(b * NH_ + h)) * DH_ + d) * S_ + s0) = pk;
      } else {                                 // head layout [B,NH,S,DH]
#pragma unroll
        for (int r = 0; r < 4; ++r) {
          int row = bm + wm * 64 + mi * 16 + lg * 4 + r;
          int b = row >> 10, s = row & 1023;
          Cb[(((size_t)(b * NH_ + h)) * S_ + s) * DH_ + d] =
              f2bf((acc[mi][ni][r] + bv) * scale);
        }
      }
    }
}

// ---- out GEMM: 64x128 tile, BK=32, 2-phase double-buffered (24KB),
// conflict-free (row>>1)&3 swizzle, fp32 output ------------------------------
__global__ __launch_bounds__(256) void out64(
    const short* __restrict__ A, const short* __restrict__ Bt,
    const float* __restrict__ bias, float* __restrict__ Cf) {
  __shared__ short As[2][64 * 32];    // 2 x 4 KB
  __shared__ short Bs[2][128 * 32];   // 2 x 8 KB
  const int K = H_, N = H_;
  const int t = threadIdx.x;
  const int l = t & 63, w = t >> 6;
  const int lr = l & 15, lg = l >> 4;
  const int lk = (lr >> 1) & 3;
  const int wm = w >> 1, wn = w & 1;   // 2x2 waves, each 32x64
  const int bm = blockIdx.x * 64, bn = blockIdx.y * 128;
  f32x4 acc[2][4];
#pragma unroll
  for (int i = 0; i < 2; ++i)
#pragma unroll
    for (int j = 0; j < 4; ++j) acc[i][j] = (f32x4){0.f, 0.f, 0.f, 0.f};
  const int sr = t >> 2;              // 0..63 (stage row)
  const int ss = ((t & 3) ^ ((sr >> 1) & 3)) * 8;   // pre-swizzled src slot
  const short* Ab = A + (size_t)(bm + sr) * K + ss;
  const short* Bb = Bt + (size_t)(bn + sr) * K + ss;

  auto stage = [&](int buf, int kb) {
    gload16(Ab + kb, (char*)&As[buf][0] + t * 16);
    gload16(Bb + kb, (char*)&Bs[buf][0] + t * 16);
    gload16(Bb + (size_t)64 * K + kb, (char*)&Bs[buf][0] + 4096 + t * 16);
  };

  stage(0, 0);
  __syncthreads();
  const int NT = K >> 5;
  for (int tt = 0; tt < NT; ++tt) {
    const int cur = tt & 1;
    bf16x8 af[2], bfr[4];
#pragma unroll
    for (int mi = 0; mi < 2; ++mi) {
      const int row = wm * 32 + mi * 16 + lr;
      af[mi] = *reinterpret_cast<const bf16x8*>(
          &As[cur][row * 32 + ((lg ^ lk) * 8)]);
    }
#pragma unroll
    for (int ni = 0; ni < 4; ++ni) {
      const int rb = wn * 64 + ni * 16 + lr;
      bfr[ni] = *reinterpret_cast<const bf16x8*>(
          &Bs[cur][rb * 32 + ((lg ^ lk) * 8)]);
    }
    if (tt + 1 < NT) stage(cur ^ 1, (tt + 1) << 5);
#pragma unroll
    for (int mi = 0; mi < 2; ++mi)
#pragma unroll
      for (int ni = 0; ni < 4; ++ni)
        acc[mi][ni] = mfma16(af[mi], bfr[ni], acc[mi][ni]);
    __syncthreads();
  }
#pragma unroll
  for (int mi = 0; mi < 2; ++mi)
#pragma unroll
    for (int ni = 0; ni < 4; ++ni) {
      int col = bn + wn * 64 + ni * 16 + lr;
      float bv = bias[col];
#pragma unroll
      for (int r = 0; r < 4; ++r) {
        int row = bm + wm * 32 + mi * 16 + lg * 4 + r;
        Cf[(size_t)row * N + col] = acc[mi][ni][r] + bv;
      }
    }
}

// ---------------- flash attention over COMPACTED keys -----------------------
// Qh (pre-scaled by (1/8)*log2e), Kh/VhT hold compacted keys (slots 0..cnt-1
// live, rest finite garbage). p = exp2(s2 + mk), mk = (j<cnt) ? -16 : -1e9
// (shift cancels in p/sum; padded slots -> p = 0 exactly). Graph factor uses
// idx to recover the original key position (compaction is order-stable, so
// orig<100 keys are exactly compacted j < cnt100).
__global__ __launch_bounds__(256) void attn(
    const short* __restrict__ Qh, const short* __restrict__ Kh,
    const short* __restrict__ VhT, const float* __restrict__ graph,
    const int* __restrict__ idx, const int* __restrict__ cnts,
    short* __restrict__ ctx) {
  __shared__ short Kb[64 * 64];
  __shared__ short Vb[64 * 64];
  __shared__ short P[4 * 16 * 64];   // per-wave 16x64, XOR-swizzled, stride 64
  __shared__ float maskf[S_];
  // T1 chunked XCD swizzle: 8 XCDs x 128 contiguous gids
  const int lin = blockIdx.x;
  const int gid = (lin & 7) * 128 + (lin >> 3);
  const int bh = gid >> 4, qt = gid & 15;
  const int b = bh >> 4, h = bh & 15;
  const int t = threadIdx.x, w = t >> 6, l = t & 63;
  const int lr = l & 15, lg = l >> 4;
  const int lx = lr & 7;
  const int q0 = qt * 64 + w * 16;      // this wave's q base
  const int qg = q0 + lr;               // lane's q (score layout: col = q)
  short* Pw = P + w * 1024;
  const int cnt = cnts[b];
  const int cnt100 = cnts[4 + b];
  const int kend = ((cnt + 63) >> 6) << 6;
  const int* idxb = idx + b * 1024;
  const short* Qrow = Qh + ((size_t)bh * S_ + qg) * DH_;
  bf16x8 qf0 = *reinterpret_cast<const bf16x8*>(Qrow + lg * 8);
  bf16x8 qf1 = *reinterpret_cast<const bf16x8*>(Qrow + 32 + lg * 8);
  f32x4 o[4];
#pragma unroll
  for (int i = 0; i < 4; ++i) o[i] = (f32x4){0.f, 0.f, 0.f, 0.f};
  float llp = 0.f;

  // staging geometry: thread t handles row rs; logical granules ga, gb=ga^4
  const int rs = t >> 2;               // 0..63
  const int ga = (t & 3) + ((rs & 1) << 2);  // 0..7
  const int gb = ga ^ 4;
  const int sw0 = ((ga ^ (rs & 7)) * 8);
  const int sw1 = ((gb ^ (rs & 7)) * 8);
  const short* Ksrc0 = Kh + ((size_t)bh * S_ + rs) * DH_ + ga * 8;
  const short* Ksrc1 = Kh + ((size_t)bh * S_ + rs) * DH_ + gb * 8;
  const short* Vsrc0 = VhT + ((size_t)bh * DH_ + rs) * S_ + ga * 8;
  const short* Vsrc1 = VhT + ((size_t)bh * DH_ + rs) * S_ + gb * 8;

  // additive table (log2 domain) from compacted count:
  // j < cnt -> -16 (uniform shift), else -1e9 (exp2 -> exactly 0)
  {
    const int s0 = t * 4;
    f32x4 mo;
    mo.x = (s0 < cnt) ? -16.f : -1.0e9f;
    mo.y = (s0 + 1 < cnt) ? -16.f : -1.0e9f;
    mo.z = (s0 + 2 < cnt) ? -16.f : -1.0e9f;
    mo.w = (s0 + 3 < cnt) ? -16.f : -1.0e9f;
    reinterpret_cast<f32x4*>(maskf)[t] = mo;
  }
  // stage chunk 0
  {
    int4 ka = *reinterpret_cast<const int4*>(Ksrc0);
    int4 kb2 = *reinterpret_cast<const int4*>(Ksrc1);
    int4 va = *reinterpret_cast<const int4*>(Vsrc0);
    int4 vb2 = *reinterpret_cast<const int4*>(Vsrc1);
    *reinterpret_cast<int4*>(&Kb[rs * 64 + sw0]) = ka;
    *reinterpret_cast<int4*>(&Kb[rs * 64 + sw1]) = kb2;
    *reinterpret_cast<int4*>(&Vb[rs * 64 + sw0]) = va;
    *reinterpret_cast<int4*>(&Vb[rs * 64 + sw1]) = vb2;
  }
  __syncthreads();

  for (int kc = 0; kc < kend; kc += 64) {
    const bool pf = (kc + 64 < kend);
    int4 ka, kb2, va, vb2;
    if (pf) {                     // prefetch next chunk into registers (T14)
      ka = *reinterpret_cast<const int4*>(Ksrc0 + (size_t)(kc + 64) * DH_);
      kb2 = *reinterpret_cast<const int4*>(Ksrc1 + (size_t)(kc + 64) * DH_);
      va = *reinterpret_cast<const int4*>(Vsrc0 + kc + 64);
      vb2 = *reinterpret_cast<const int4*>(Vsrc1 + kc + 64);
    }
    // --- swapped QK^T from LDS: lane holds q=lr, k = mf*16+lg*4+r
    f32x4 sacc[4];
    __builtin_amdgcn_s_setprio(1);
#pragma unroll
    for (int mf = 0; mf < 4; ++mf) {
      const int rk = mf * 16 + lr;
      bf16x8 k0 = *reinterpret_cast<const bf16x8*>(
          &Kb[rk * 64 + ((lg ^ lx) * 8)]);
      bf16x8 k1 = *reinterpret_cast<const bf16x8*>(
          &Kb[rk * 64 + (((4 + lg) ^ lx) * 8)]);
      f32x4 sa = (f32x4){0.f, 0.f, 0.f, 0.f};
      sa = mfma16(k0, qf0, sa);
      sa = mfma16(k1, qf1, sa);
      sacc[mf] = sa;
    }
    __builtin_amdgcn_s_setprio(0);
    // --- graph factor (orig index via idx), additive mask, exp2, pack to P
    const bool gblk = (q0 < G_) && (kc < cnt100);
    const int pw0 = lr * 64 + (lg & 1) * 4;
#pragma unroll
    for (int mf = 0; mf < 4; ++mf) {
      f32x4 mk = *reinterpret_cast<const f32x4*>(&maskf[kc + mf * 16 + lg * 4]);
      f32x4 sa = sacc[mf];
      if (gblk) {
#pragma unroll
        for (int r = 0; r < 4; ++r) {
          int kgc = kc + mf * 16 + lg * 4 + r;
          if (qg < G_ && kgc < cnt100)
            sa[r] *= (1.f - graph[((size_t)b * G_ + qg) * G_ + idxb[kgc]]);
        }
      }
      float e0 = exp2hw(sa[0] + mk[0]);
      float e1 = exp2hw(sa[1] + mk[1]);
      float e2 = exp2hw(sa[2] + mk[2]);
      float e3 = exp2hw(sa[3] + mk[3]);
      llp += (e0 + e1) + (e2 + e3);
      int2 pk2;
      pk2.x = (int)cvtpk(e0, e1);
      pk2.y = (int)cvtpk(e2, e3);
      *reinterpret_cast<int2*>(
          &Pw[pw0 + (((2 * mf + (lg >> 1)) ^ lx) * 8)]) = pk2;
    }
    // --- PV from LDS: O[16q][64d] += P[16q,64k] @ V[64k,64d]
    __builtin_amdgcn_s_setprio(1);
#pragma unroll
    for (int ks = 0; ks < 2; ++ks) {
      bf16x8 pa = *reinterpret_cast<const bf16x8*>(
          &Pw[lr * 64 + (((ks * 4 + lg) ^ lx) * 8)]);
#pragma unroll
      for (int nf = 0; nf < 4; ++nf) {
        const int rv = nf * 16 + lr;
        bf16x8 vfr = *reinterpret_cast<const bf16x8*>(
            &Vb[rv * 64 + (((ks * 4 + lg) ^ lx) * 8)]);
        o[nf] = mfma16(pa, vfr, o[nf]);
      }
    }
    __builtin_amdgcn_s_setprio(0);
    if (pf) {
      __syncthreads();   // all waves done reading Kb/Vb for this chunk
      *reinterpret_cast<int4*>(&Kb[rs * 64 + sw0]) = ka;
      *reinterpret_cast<int4*>(&Kb[rs * 64 + sw1]) = kb2;
      *reinterpret_cast<int4*>(&Vb[rs * 64 + sw0]) = va;
      *reinterpret_cast<int4*>(&Vb[rs * 64 + sw1]) = vb2;
      __syncthreads();   // staged data visible
    }
  }
  // single cross-lane reduction at the end
  llp += __shfl_xor(llp, 16);
  llp += __shfl_xor(llp, 32);
  float rinv[4];
#pragma unroll
  for (int r = 0; r < 4; ++r)
    rinv[r] = __builtin_amdgcn_rcpf(__shfl(llp, lg * 4 + r, 64));
#pragma unroll
  for (int nf = 0; nf < 4; ++nf)
#pragma unroll
    for (int r = 0; r < 4; ++r) {
      float val = o[nf][r] * rinv[r];
      ctx[((size_t)b * S_ + q0 + lg * 4 + r) * H_ + h * DH_ + nf * 16 + lr] =
          f2bf(val);
    }
}

extern "C" void kernel_launch(void* const* d_in, const int* in_sizes, int n_in,
                              void* d_out, int out_size, void* d_ws, size_t ws_size,
                              hipStream_t stream) {
  const int B = in_sizes[0] / (S_ * H_);   // 4
  const int M = B * S_;                    // 4096
  const float* v    = (const float*)d_in[0];
  const float* k    = (const float*)d_in[1];
  const float* q    = (const float*)d_in[2];
  const int*   mask = (const int*)d_in[3];
  const float* graph= (const float*)d_in[4];
  const float* Wq   = (const float*)d_in[5];
  const float* bq   = (const float*)d_in[6];
  const float* Wk   = (const float*)d_in[7];
  const float* bk   = (const float*)d_in[8];
  const float* Wv   = (const float*)d_in[9];
  const float* bv   = (const float*)d_in[10];
  const float* Wm   = (const float*)d_in[11];
  const float* bm   = (const float*)d_in[12];

  short* ws = (short*)d_ws;
  const size_t WSZ = (size_t)H_ * H_;     // 1M elems per transposed weight
  const size_t TSZ = (size_t)M * H_;      // 4M elems per activation tensor
  short* WqT = ws;
  short* WkT = ws + WSZ;
  short* WvT = ws + 2 * WSZ;
  short* WmT = ws + 3 * WSZ;
  short* Qh  = ws + 4 * WSZ;
  short* Kh  = Qh + TSZ;
  short* VhT = Kh + TSZ;
  short* ctx = VhT + TSZ;
  int*   idxw = (int*)(ctx + TSZ);
  int*   cntw = idxw + 4 * 1024;
  if (ws_size < (4 * WSZ + 4 * TSZ) * sizeof(short) + (4 * 1024 + 8) * 4) {
    fprintf(stderr, "kernel_launch: ws too small (%zu)\n", ws_size);
    return;
  }

  compact<<<dim3(4), 256, 0, stream>>>(mask, idxw, cntw);
  transpose_w<<<dim3(H_ / 64, H_ / 64, 4), 256, 0, stream>>>(
      Wq, Wk, Wv, Wm, WqT, WkT, WvT, WmT);
  qkv128r<<<dim3(M / 128, H_ / 128, 3), 256, 0, stream>>>(
      q, k, v, WqT, WkT, WvT, bq, bk, bv, Qh, Kh, VhT, idxw, cntw);
  attn<<<dim3(1024), 256, 0, stream>>>(Qh, Kh, VhT, graph, idxw, cntw, ctx);
  out64<<<dim3(M / 64, H_ / 128), 256, 0, stream>>>(
      ctx, WmT, bm, (float*)d_out);
}